// Round 7
// baseline (348.257 us; speedup 1.0000x reference)
//
#include <hip/hip_runtime.h>

// Problem constants
#define B_    4096
#define T_    32
#define OUT_  8
#define BTILE 32
#define NBLK  (B_ / BTILE)   // 128 main-kernel blocks

typedef _Float16 f16;
typedef _Float16 f16x4 __attribute__((ext_vector_type(4)));
typedef _Float16 f16x8 __attribute__((ext_vector_type(8)));
typedef float    f32x4 __attribute__((ext_vector_type(4)));

#define GPTR(p) ((const __attribute__((address_space(1))) void*)(p))
#define LPTR(p) ((__attribute__((address_space(3))) void*)(p))

// ---- workspace layout (bytes). Total ~25.3 MB ----
// [0, 8448): f32 weights (WA 1024, WO 1024, biasA 16 @f32idx 2048, biasB 16 @f32idx 2112)
#define WS_AENC 16384u                    // [B*T][16] f16 = 4 MB
#define WS_OENC (WS_AENC + 4194304u)      // 4 MB
#define WS_H    (WS_OENC + 4194304u)      // f16 relaid H: 512 sub-slabs x 32 KB + 2 pad
// sub-slab (t, q) holds p-pair (2q, 2q+1); granule (1 KB) index within sub-slab:
//   g = sq*8 + nf*4 + pl*2 + ss   (wave (sq,nf) owns g in [w*4, w*4+4), w = sq*2+nf)
// granule byte lane*16, slot h*4+r = Ht[p=2q+pl][j=2(2sq+ss)+h][kk=g4*4+r][l=nf*16+m16] * (1/8)

// ------------------- prep 1: fuse encoder weights -------------------
__global__ void k_fuse_w(const float* __restrict__ Wa0, const float* __restrict__ ba0,
                         const float* __restrict__ Wa1, const float* __restrict__ ba1,
                         const float* __restrict__ Wo0, const float* __restrict__ bo0,
                         const float* __restrict__ Wo1, const float* __restrict__ bo1,
                         float* __restrict__ ws) {
  const int tid = threadIdx.x;  // 256 threads, 1 block
  for (int idx = tid; idx < 1024; idx += 256) {
    const int d = idx >> 4, j = idx & 15;
    float s = 0.f, s2 = 0.f;
    for (int h = 0; h < 128; ++h) {
      s  += Wa0[d * 128 + h] * Wa1[h * 16 + j];
      s2 += Wo0[d * 128 + h] * Wo1[h * 16 + j];
    }
    ws[idx] = s;
    ws[1024 + idx] = s2;
  }
  if (tid < 16) {
    float s = 0.f, s2 = 0.f;
    for (int h = 0; h < 128; ++h) {
      s  += ba0[h] * Wa1[h * 16 + tid];
      s2 += bo0[h] * Wo1[h * 16 + tid];
    }
    ws[2048 + tid] = s + ba1[tid];
    ws[2112 + tid] = s2 + bo1[tid];
  }
}

// ------------------- prep 2: MFMA encoder (f16 in, f32 acc) -------------------
__global__ void k_encode(const float* __restrict__ action, const float* __restrict__ obs,
                         const float* __restrict__ ws,
                         f16* __restrict__ aenc, f16* __restrict__ oenc) {
  const int tid = threadIdx.x;
  const int lane = tid & 63;
  const int v = tid >> 6;
  const int m16 = lane & 15, g4 = lane >> 4;
  const int bt0 = blockIdx.x * 64 + v * 16;

  f16x8 wbA[2], wbB[2];
  #pragma unroll
  for (int ks = 0; ks < 2; ++ks)
    #pragma unroll
    for (int h = 0; h < 2; ++h)
      #pragma unroll
      for (int r = 0; r < 4; ++r) {
        const int d = ks * 32 + h * 16 + g4 * 4 + r;
        wbA[ks][h * 4 + r] = (f16)ws[d * 16 + m16];
        wbB[ks][h * 4 + r] = (f16)ws[1024 + d * 16 + m16];
      }
  const float biasA = ws[2048 + m16], biasB = ws[2112 + m16];
  f32x4 accA = {biasA, biasA, biasA, biasA};
  f32x4 accB = {biasB, biasB, biasB, biasB};

  const float* ar = action + (size_t)(bt0 + m16) * 64;
  const float* br = obs    + (size_t)(bt0 + m16) * 64;
  #pragma unroll
  for (int ks = 0; ks < 2; ++ks) {
    f16x8 aa, oo;
    #pragma unroll
    for (int h = 0; h < 2; ++h) {
      const f32x4 a4 = *(const f32x4*)(ar + ks * 32 + h * 16 + g4 * 4);
      const f32x4 o4 = *(const f32x4*)(br + ks * 32 + h * 16 + g4 * 4);
      #pragma unroll
      for (int r = 0; r < 4; ++r) { aa[h * 4 + r] = (f16)a4[r]; oo[h * 4 + r] = (f16)o4[r]; }
    }
    accA = __builtin_amdgcn_mfma_f32_16x16x32_f16(aa, wbA[ks], accA, 0, 0, 0);
    accB = __builtin_amdgcn_mfma_f32_16x16x32_f16(oo, wbB[ks], accB, 0, 0, 0);
  }
  #pragma unroll
  for (int r = 0; r < 4; ++r) {
    aenc[(size_t)(bt0 + g4 * 4 + r) * 16 + m16] = (f16)accA[r];
    oenc[(size_t)(bt0 + g4 * 4 + r) * 16 + m16] = (f16)accB[r];
  }
}

// ------------------- prep 3: relayout H -> f16 per-wave granules, scaled by 1/8 -------------------
__global__ void k_hprep(const float* __restrict__ Hf, const float* __restrict__ Hm,
                        const float* __restrict__ Hl, f16* __restrict__ hdst) {
  const int x = blockIdx.x * 256 + threadIdx.x;     // < 1048576
  const int lane = x & 63;
  const int gid = x >> 6;                           // 16384 granules
  const int g = gid & 31, q = (gid >> 5) & 15, t = gid >> 9;
  const int sq = g >> 3, nf = (g >> 2) & 1, pl = (g >> 1) & 1, ss = g & 1;
  const int p = q * 2 + pl;
  const int m16 = lane & 15, g4 = lane >> 4;
  const int l = nf * 16 + m16;
  f16x8 gout;
  #pragma unroll
  for (int h = 0; h < 2; ++h) {
    const int j = 2 * (sq * 2 + ss) + h;
    #pragma unroll
    for (int r = 0; r < 4; ++r) {
      const int kk = g4 * 4 + r;
      float vsrc;
      if (t == 0)       vsrc = (p == 0) ? Hf[(j * 16 + kk) * 32 + l] : 0.f;
      else if (t == 31) vsrc = (l < 8) ? Hl[((p * 16 + j) * 16 + kk) * 8 + l] : 0.f;
      else              vsrc = Hm[((((size_t)(t - 1) * 32 + p) * 16 + j) * 16 + kk) * 32 + l];
      gout[h * 4 + r] = (f16)(vsrc * 0.125f);
    }
  }
  *(f16x8*)((char*)hdst + (size_t)x * 16) = gout;   // layout == linear granule order
}

// ------------------- main fused kernel -------------------
// 128 blocks x 512 threads (8 waves, 2/SIMD). Wave w = (sq = w>>1, nf = w&1) owns its
// private 4 KB per p-pair. Barrier-FREE K-loop: each wave DMA-stages its own granules
// into its private 16 KB LDS ring (global_load_lds) and self-syncs with counted
// per-wave vmcnt(8) (never 0). Only the per-t chain reduce uses (raw) barriers.
__launch_bounds__(512)
__global__ void k_main(const f16* __restrict__ aenc, const f16* __restrict__ oenc,
                       const char* __restrict__ hws, float* __restrict__ out) {
  __shared__ __align__(16) char sbuf[4][32768];     // 128 KB: ring of 4; wave w owns [w*4K, +4K)
  __shared__ float cpart[8][2][16][20];             // 20.5 KB [wave][mf][l-col][b-row]
  __shared__ float cfull[32][33];                   // 4.2 KB [p][b]

  const int tid  = threadIdx.x;
  const int lane = tid & 63;
  const int w    = tid >> 6;       // 0..7
  const int m16  = lane & 15;
  const int g4   = lane >> 4;      // 0..3
  const int sq   = w >> 1;         // 0..3 (j-quarter)
  const int b0   = blockIdx.x * BTILE;

  // init chain state: c[p][b] = (p == 0)
  for (int k2 = tid; k2 < 1024; k2 += 512)
    cfull[k2 >> 5][k2 & 31] = ((k2 >> 5) == 0) ? 1.f : 0.f;

#define STAGE(PCX) do {                                                        \
    const int Qs_ = (PCX) ? (PCX) + 15 : 0;                                    \
    const size_t sb_ = (size_t)Qs_ * 32768 + (size_t)w * 4096 + (size_t)lane * 16; \
    char* db_ = &sbuf[(PCX) & 3][w * 4096];                                    \
    _Pragma("unroll")                                                          \
    for (int i_ = 0; i_ < 4; ++i_)                                             \
      __builtin_amdgcn_global_load_lds(GPTR(hws + sb_ + i_ * 1024),            \
                                       LPTR(db_ + i_ * 1024), 16, 0, 0);       \
  } while (0)

  // prologue: stage phases 0 and 1 (per-wave private)
  STAGE(0);
  STAGE(1);

  // enc regs for t=0: per-lane a (4 j's = 4sq..4sq+3) and o (4 kk's = 4g4..) per mf
  f16x4 av0 = *(const f16x4*)(aenc + ((size_t)(b0 + m16) * T_ + 0) * 16 + 4 * sq);
  f16x4 av1 = *(const f16x4*)(aenc + ((size_t)(b0 + 16 + m16) * T_ + 0) * 16 + 4 * sq);
  f16x4 ov0 = *(const f16x4*)(oenc + ((size_t)(b0 + m16) * T_ + 0) * 16 + g4 * 4);
  f16x4 ov1 = *(const f16x4*)(oenc + ((size_t)(b0 + 16 + m16) * T_ + 0) * 16 + g4 * 4);

  // cfull init visible to all waves before first phase
  asm volatile("s_waitcnt lgkmcnt(0)" ::: "memory");
  __builtin_amdgcn_s_barrier();

  int pc = 0;
  #pragma clang loop unroll(disable)
  for (int t = 0; t < T_; ++t) {
    const int nq = (t == 0) ? 1 : 16;
    f32x4 acc0 = {0.f, 0.f, 0.f, 0.f};   // mf = 0 (b rows b0..b0+15), col l = nf*16+m16
    f32x4 acc1 = {0.f, 0.f, 0.f, 0.f};   // mf = 1

    for (int qq = 0; qq < nq; ++qq, ++pc) {
      const int Q = pc ? pc + 15 : 0;
      const int qi = Q & 15;                          // p-pair index within t
      STAGE(pc + 2);                                  // max PCX=498 -> pad sub-slabs 512/513
      // per-wave counted wait: slot pc complete once <=8 newer VMEM ops outstanding
      asm volatile("s_waitcnt vmcnt(8)" ::: "memory");

      const char* gb = &sbuf[pc & 3][w * 4096];
      const f16 c00 = (f16)cfull[2 * qi][m16];
      const f16 c01 = (f16)cfull[2 * qi][16 + m16];
      const f16 c10 = (f16)cfull[2 * qi + 1][m16];
      const f16 c11 = (f16)cfull[2 * qi + 1][16 + m16];

      #pragma unroll
      for (int pl = 0; pl < 2; ++pl) {
        const f16 ca = pl ? c10 : c00;   // c for (p = 2qi+pl, b = m16)      -> mf0
        const f16 cb = pl ? c11 : c01;   // c for (p = 2qi+pl, b = 16+m16)   -> mf1
        #pragma unroll
        for (int ss = 0; ss < 2; ++ss) {
          const f16x8 bf = *(const f16x8*)(gb + (pl * 2 + ss) * 1024 + lane * 16);
          const f16 a00 = ca * av0[2 * ss], a01 = ca * av0[2 * ss + 1];
          const f16 a10 = cb * av1[2 * ss], a11 = cb * av1[2 * ss + 1];
          f16x8 af0, af1;
          #pragma unroll
          for (int r = 0; r < 4; ++r) {
            af0[r] = a00 * ov0[r]; af0[4 + r] = a01 * ov0[r];
            af1[r] = a10 * ov1[r]; af1[4 + r] = a11 * ov1[r];
          }
          acc0 = __builtin_amdgcn_mfma_f32_16x16x32_f16(af0, bf, acc0, 0, 0, 0);
          acc1 = __builtin_amdgcn_mfma_f32_16x16x32_f16(af1, bf, acc1, 0, 0, 0);
        }
      }
    }

    // ---- chain phase: cross-wave reduce (raw barriers; DMA stays in flight) ----
    // D: col = m16 (l within nf), rows = mf*16 + g4*4 + r
    *(f32x4*)&cpart[w][0][m16][g4 * 4] = acc0;
    *(f32x4*)&cpart[w][1][m16][g4 * 4] = acc1;

    // preload enc for t+1 (regular VMEM; only makes later counted waits conservative)
    const int tnn = (t < 31) ? t + 1 : 31;
    av0 = *(const f16x4*)(aenc + ((size_t)(b0 + m16) * T_ + tnn) * 16 + 4 * sq);
    av1 = *(const f16x4*)(aenc + ((size_t)(b0 + 16 + m16) * T_ + tnn) * 16 + 4 * sq);
    ov0 = *(const f16x4*)(oenc + ((size_t)(b0 + m16) * T_ + tnn) * 16 + g4 * 4);
    ov1 = *(const f16x4*)(oenc + ((size_t)(b0 + 16 + m16) * T_ + tnn) * 16 + g4 * 4);

    asm volatile("s_waitcnt lgkmcnt(0)" ::: "memory");
    __builtin_amdgcn_s_barrier();
    #pragma unroll
    for (int rep = 0; rep < 2; ++rep) {
      const int e = tid + rep * 512;
      const int bb = e & 31, L = e >> 5;
      const int mfi = bb >> 4, row = bb & 15, nfi = L >> 4, col = L & 15;
      const float ssum = cpart[0 * 2 + nfi][mfi][col][row] + cpart[1 * 2 + nfi][mfi][col][row]
                       + cpart[2 * 2 + nfi][mfi][col][row] + cpart[3 * 2 + nfi][mfi][col][row];
      if (t < 31) cfull[L][bb] = ssum;
      else if (L < 8) out[(size_t)(b0 + bb) * 8 + L] = ssum * 0x1p96f;  // undo 8^-32 scaling
    }
    asm volatile("s_waitcnt lgkmcnt(0)" ::: "memory");
    __builtin_amdgcn_s_barrier();
  }
  // drain outstanding DMA before LDS dealloc
  asm volatile("s_waitcnt vmcnt(0)" ::: "memory");
#undef STAGE
}

extern "C" void kernel_launch(void* const* d_in, const int* in_sizes, int n_in,
                              void* d_out, int out_size, void* d_ws, size_t ws_size,
                              hipStream_t stream) {
  (void)in_sizes; (void)n_in; (void)out_size; (void)ws_size;
  const float* action = (const float*)d_in[0];
  const float* obs    = (const float*)d_in[1];
  const float* Wa0 = (const float*)d_in[2];
  const float* ba0 = (const float*)d_in[3];
  const float* Wa1 = (const float*)d_in[4];
  const float* ba1 = (const float*)d_in[5];
  const float* Wo0 = (const float*)d_in[6];
  const float* bo0 = (const float*)d_in[7];
  const float* Wo1 = (const float*)d_in[8];
  const float* bo1 = (const float*)d_in[9];
  const float* Hf  = (const float*)d_in[10];
  const float* Hm  = (const float*)d_in[11];
  const float* Hl  = (const float*)d_in[12];
  char*  ws  = (char*)d_ws;
  float* out = (float*)d_out;

  k_fuse_w<<<1, 256, 0, stream>>>(Wa0, ba0, Wa1, ba1, Wo0, bo0, Wo1, bo1, (float*)ws);
  k_encode<<<(B_ * T_) / 64, 256, 0, stream>>>(action, obs, (const float*)ws,
                                               (f16*)(ws + WS_AENC), (f16*)(ws + WS_OENC));
  k_hprep<<<4096, 256, 0, stream>>>(Hf, Hm, Hl, (f16*)(ws + WS_H));
  k_main<<<NBLK, 512, 0, stream>>>((const f16*)(ws + WS_AENC), (const f16*)(ws + WS_OENC),
                                   (const char*)(ws + WS_H), out);
}

// Round 8
// 223.999 us; speedup vs baseline: 1.5547x; 1.5547x over previous
//
#include <hip/hip_runtime.h>

// Problem constants
#define B_    4096
#define T_    32
#define OUT_  8
#define BTILE 32

typedef _Float16 f16;
typedef _Float16 f16x4 __attribute__((ext_vector_type(4)));
typedef _Float16 f16x8 __attribute__((ext_vector_type(8)));
typedef float    f32x4 __attribute__((ext_vector_type(4)));

#define MFMA16(a, b, c) __builtin_amdgcn_mfma_f32_16x16x32_f16((a), (b), (c), 0, 0, 0)

// ---- workspace layout (bytes). Total ~25 MB ----
// [0, 8448): f32 weights (WA 1024, WO 1024, biasA @f32 2048, biasB @f32 2112)
#define WS_AENC 16384u                    // [B*T][16] f16 = 4 MB
#define WS_OENC (WS_AENC + 4194304u)      // 4 MB
#define WS_H    (WS_OENC + 4194304u)      // f16 relaid H: 16 MB
#define WS_U    (WS_H + 16842752u)        // u exchange: 128 bt x 32 b x 32 m f32 = 512 KB
#define WS_FLAG (WS_U + 524288u)          // 128 ints
// H granule (1 KB) per (t, p, sl, nf): byte ((t*32+p)*16 + sl*2 + nf)*1024 + lane*16
// slot h*4+r = Ht[p][j=2sl+h][kk=g4*4+r][l=nf*16+m16] * (1/8)   (t=0 rows p>0 zero-padded,
// t=31 cols l>=8 zero-padded)

// ------------------- prep 1: fuse encoder weights -------------------
__global__ void k_fuse_w(const float* __restrict__ Wa0, const float* __restrict__ ba0,
                         const float* __restrict__ Wa1, const float* __restrict__ ba1,
                         const float* __restrict__ Wo0, const float* __restrict__ bo0,
                         const float* __restrict__ Wo1, const float* __restrict__ bo1,
                         float* __restrict__ ws) {
  const int tid = threadIdx.x;  // 256 threads, 1 block
  for (int idx = tid; idx < 1024; idx += 256) {
    const int d = idx >> 4, j = idx & 15;
    float s = 0.f, s2 = 0.f;
    for (int h = 0; h < 128; ++h) {
      s  += Wa0[d * 128 + h] * Wa1[h * 16 + j];
      s2 += Wo0[d * 128 + h] * Wo1[h * 16 + j];
    }
    ws[idx] = s;
    ws[1024 + idx] = s2;
  }
  if (tid < 16) {
    float s = 0.f, s2 = 0.f;
    for (int h = 0; h < 128; ++h) {
      s  += ba0[h] * Wa1[h * 16 + tid];
      s2 += bo0[h] * Wo1[h * 16 + tid];
    }
    ws[2048 + tid] = s + ba1[tid];
    ws[2112 + tid] = s2 + bo1[tid];
  }
}

// ------------------- prep 2: MFMA encoder (f16 in, f32 acc) -------------------
__global__ void k_encode(const float* __restrict__ action, const float* __restrict__ obs,
                         const float* __restrict__ ws,
                         f16* __restrict__ aenc, f16* __restrict__ oenc) {
  const int tid = threadIdx.x;
  const int lane = tid & 63;
  const int v = tid >> 6;
  const int m16 = lane & 15, g4 = lane >> 4;
  const int bt0 = blockIdx.x * 64 + v * 16;

  f16x8 wbA[2], wbB[2];
  #pragma unroll
  for (int ks = 0; ks < 2; ++ks)
    #pragma unroll
    for (int h = 0; h < 2; ++h)
      #pragma unroll
      for (int r = 0; r < 4; ++r) {
        const int d = ks * 32 + h * 16 + g4 * 4 + r;
        wbA[ks][h * 4 + r] = (f16)ws[d * 16 + m16];
        wbB[ks][h * 4 + r] = (f16)ws[1024 + d * 16 + m16];
      }
  const float biasA = ws[2048 + m16], biasB = ws[2112 + m16];
  f32x4 accA = {biasA, biasA, biasA, biasA};
  f32x4 accB = {biasB, biasB, biasB, biasB};

  const float* ar = action + (size_t)(bt0 + m16) * 64;
  const float* br = obs    + (size_t)(bt0 + m16) * 64;
  #pragma unroll
  for (int ks = 0; ks < 2; ++ks) {
    f16x8 aa, oo;
    #pragma unroll
    for (int h = 0; h < 2; ++h) {
      const f32x4 a4 = *(const f32x4*)(ar + ks * 32 + h * 16 + g4 * 4);
      const f32x4 o4 = *(const f32x4*)(br + ks * 32 + h * 16 + g4 * 4);
      #pragma unroll
      for (int r = 0; r < 4; ++r) { aa[h * 4 + r] = (f16)a4[r]; oo[h * 4 + r] = (f16)o4[r]; }
    }
    accA = MFMA16(aa, wbA[ks], accA);
    accB = MFMA16(oo, wbB[ks], accB);
  }
  #pragma unroll
  for (int r = 0; r < 4; ++r) {
    aenc[(size_t)(bt0 + g4 * 4 + r) * 16 + m16] = (f16)accA[r];
    oenc[(size_t)(bt0 + g4 * 4 + r) * 16 + m16] = (f16)accB[r];
  }
}

// ------------------- prep 3: relayout H -> f16 granules, scaled by 1/8 -------------------
__global__ void k_hprep(const float* __restrict__ Hf, const float* __restrict__ Hm,
                        const float* __restrict__ Hl, f16* __restrict__ hdst) {
  const int x = blockIdx.x * 256 + threadIdx.x;     // < 1048576
  const int lane = x & 63;
  const int gid = x >> 6;
  const int nf = gid & 1, s = (gid >> 1) & 7, p = (gid >> 4) & 31, t = gid >> 9;
  const int m16 = lane & 15, g4 = lane >> 4;
  const int l = nf * 16 + m16;
  f16x8 gout;
  #pragma unroll
  for (int h = 0; h < 2; ++h) {
    const int j = 2 * s + h;
    #pragma unroll
    for (int r = 0; r < 4; ++r) {
      const int kk = g4 * 4 + r;
      float vsrc;
      if (t == 0)       vsrc = (p == 0) ? Hf[(j * 16 + kk) * 32 + l] : 0.f;
      else if (t == 31) vsrc = (l < 8) ? Hl[((p * 16 + j) * 16 + kk) * 8 + l] : 0.f;
      else              vsrc = Hm[((((size_t)(t - 1) * 32 + p) * 16 + j) * 16 + kk) * 32 + l];
      gout[h * 4 + r] = (f16)(vsrc * 0.125f);
    }
  }
  *(f16x8*)((char*)hdst + (size_t)x * 16) = gout;
}

// ------------------- main fused kernel: associative 2-way T-split -------------------
// 256 blocks x 512 threads (1 block/CU, co-resident). Block (bt, g): b-rows [32bt,32bt+32),
// t in [16g, 16g+16). Computes W_g = product of its 16 contracted cores M_t (32x32 per b)
// fully in LDS (f16). Group 0's W has only row 0 alive (H_0 padding); it exports
// u = W0[0,:] via agent-scope atomics; group 1 folds out = u . W1.
// LDS index for W/M (serves both A- and B-fragments):
//   idx(b, k, n) = b*1024 + ((k>>2)&3)*256 + n*8 + (k>>4)*4 + (k&3)    [f16 elements]
__launch_bounds__(512)
__global__ void k_main(const f16* __restrict__ aenc, const f16* __restrict__ oenc,
                       const char* __restrict__ hws, float* __restrict__ uex,
                       int* __restrict__ flag, float* __restrict__ out) {
  __shared__ __align__(16) f16 Wl[32768];   // 64 KB
  __shared__ __align__(16) f16 Ml[32768];   // 64 KB
  __shared__ float u_lds[1024];             // 4 KB

  const int tid  = threadIdx.x;
  const int lane = tid & 63;
  const int w    = tid >> 6;       // 0..7 ; wave owns p in [4w, 4w+4)
  const int m16  = lane & 15;
  const int g4   = lane >> 4;
  const int bt   = blockIdx.x >> 1;
  const int g    = blockIdx.x & 1;
  const int b0   = bt * BTILE;
  const int t0   = g * 16;

  // ---- enc regs for t = t0 ----
  const f16* ap0 = aenc + ((size_t)(b0 + m16) * T_ + t0) * 16;
  const f16* ap1 = aenc + ((size_t)(b0 + 16 + m16) * T_ + t0) * 16;
  f16x8 aL0 = *(const f16x8*)ap0, aH0 = *(const f16x8*)(ap0 + 8);
  f16x8 aL1 = *(const f16x8*)ap1, aH1 = *(const f16x8*)(ap1 + 8);
  f16x4 ovA = *(const f16x4*)(oenc + ((size_t)(b0 + m16) * T_ + t0) * 16 + g4 * 4);
  f16x4 ovB = *(const f16x4*)(oenc + ((size_t)(b0 + 16 + m16) * T_ + t0) * 16 + g4 * 4);

  const char* hl = hws + (size_t)lane * 16;
  const f32x4 zz = {0.f, 0.f, 0.f, 0.f};

  f16x8 bufA[8], bufB[8];
  {
    const char* ga = hl + (size_t)((t0 * 32 + 4 * w) * 16) * 1024;
    #pragma unroll
    for (int i = 0; i < 8; ++i) bufA[i] = *(const f16x8*)(ga + i * 1024);
  }

  #pragma clang loop unroll(disable)
  for (int tau = 0; tau < 16; ++tau) {
    const int t = t0 + tau;
    // ---- build E fragments (no c — reused across all p) ----
    f16x8 efr0[8], efr1[8];
    #pragma unroll
    for (int sl = 0; sl < 8; ++sl) {
      const f16 a00 = (sl < 4) ? aL0[2 * sl]     : aH0[2 * sl - 8];
      const f16 a01 = (sl < 4) ? aL0[2 * sl + 1] : aH0[2 * sl - 7];
      const f16 a10 = (sl < 4) ? aL1[2 * sl]     : aH1[2 * sl - 8];
      const f16 a11 = (sl < 4) ? aL1[2 * sl + 1] : aH1[2 * sl - 7];
      #pragma unroll
      for (int r = 0; r < 4; ++r) {
        efr0[sl][r] = a00 * ovA[r]; efr0[sl][4 + r] = a01 * ovA[r];
        efr1[sl][r] = a10 * ovB[r]; efr1[sl][4 + r] = a11 * ovB[r];
      }
    }
    // prefetch next-τ enc (enc regs dead after E build)
    const int tn = (tau < 15) ? t + 1 : t;
    {
      const f16* an0 = aenc + ((size_t)(b0 + m16) * T_ + tn) * 16;
      const f16* an1 = aenc + ((size_t)(b0 + 16 + m16) * T_ + tn) * 16;
      aL0 = *(const f16x8*)an0; aH0 = *(const f16x8*)(an0 + 8);
      aL1 = *(const f16x8*)an1; aH1 = *(const f16x8*)(an1 + 8);
      ovA = *(const f16x4*)(oenc + ((size_t)(b0 + m16) * T_ + tn) * 16 + g4 * 4);
      ovB = *(const f16x4*)(oenc + ((size_t)(b0 + 16 + m16) * T_ + tn) * 16 + g4 * 4);
    }

    // ---- form M rows p = 4w..4w+3 (half-p double-buffered B-frag stream) ----
    #pragma unroll
    for (int pp = 0; pp < 4; ++pp) {
      const int p = 4 * w + pp;
      f32x4 a00 = zz, a01 = zz, a10 = zz, a11 = zz;
      {
        const char* gb = hl + ((size_t)((t * 32 + p) * 16) + 8) * 1024;
        #pragma unroll
        for (int i = 0; i < 8; ++i) bufB[i] = *(const f16x8*)(gb + i * 1024);
      }
      #pragma unroll
      for (int sl = 0; sl < 4; ++sl) {
        a00 = MFMA16(efr0[sl], bufA[sl * 2 + 0], a00);
        a10 = MFMA16(efr1[sl], bufA[sl * 2 + 0], a10);
        a01 = MFMA16(efr0[sl], bufA[sl * 2 + 1], a01);
        a11 = MFMA16(efr1[sl], bufA[sl * 2 + 1], a11);
      }
      {
        const int pnext = (pp < 3) ? p + 1 : 4 * w;
        const int tnext = (pp < 3) ? t : tn;
        const char* ga = hl + (size_t)((tnext * 32 + pnext) * 16) * 1024;
        #pragma unroll
        for (int i = 0; i < 8; ++i) bufA[i] = *(const f16x8*)(ga + i * 1024);
      }
      #pragma unroll
      for (int sl = 4; sl < 8; ++sl) {
        a00 = MFMA16(efr0[sl], bufB[(sl - 4) * 2 + 0], a00);
        a10 = MFMA16(efr1[sl], bufB[(sl - 4) * 2 + 0], a10);
        a01 = MFMA16(efr0[sl], bufB[(sl - 4) * 2 + 1], a01);
        a11 = MFMA16(efr1[sl], bufB[(sl - 4) * 2 + 1], a11);
      }
      // store M p-row: idx(b, k=p, n=l)
      const int pko = ((p >> 2) & 3) * 256 + (p >> 4) * 4 + (p & 3);
      #pragma unroll
      for (int r = 0; r < 4; ++r) {
        const int bA = (g4 * 4 + r) * 1024, bB = (16 + g4 * 4 + r) * 1024;
        Ml[bA + pko + m16 * 8]        = (f16)a00[r];
        Ml[bA + pko + (16 + m16) * 8] = (f16)a01[r];
        Ml[bB + pko + m16 * 8]        = (f16)a10[r];
        Ml[bB + pko + (16 + m16) * 8] = (f16)a11[r];
      }
    }
    asm volatile("s_waitcnt lgkmcnt(0)" ::: "memory");
    __builtin_amdgcn_s_barrier();

    if (tau == 0) {
      // W := M (store-transposed into W's (k=next-contract, n=row) format)
      #pragma unroll
      for (int rep = 0; rep < 64; ++rep) {
        const int e = tid + rep * 512;
        const int b = e >> 10, k = (e >> 5) & 31, rho = e & 31;
        Wl[b * 1024 + ((k >> 2) & 3) * 256 + rho * 8 + (k >> 4) * 4 + (k & 3)] =
          Ml[b * 1024 + ((rho >> 2) & 3) * 256 + k * 8 + (rho >> 4) * 4 + (rho & 3)];
      }
      asm volatile("s_waitcnt lgkmcnt(0)" ::: "memory");
      __builtin_amdgcn_s_barrier();
    } else {
      // W <- W*M : wave w handles b in [4w, 4w+4); K=32 in one MFMA per tile
      f32x4 n00[4], n01[4], n10[4], n11[4];
      #pragma unroll
      for (int bb = 0; bb < 4; ++bb) {
        const int bx = (4 * w + bb) * 1024 + g4 * 256;
        const f16x8 A0 = *(const f16x8*)&Wl[bx + m16 * 8];
        const f16x8 A1 = *(const f16x8*)&Wl[bx + (16 + m16) * 8];
        const f16x8 B0 = *(const f16x8*)&Ml[bx + m16 * 8];
        const f16x8 B1 = *(const f16x8*)&Ml[bx + (16 + m16) * 8];
        n00[bb] = MFMA16(A0, B0, zz);
        n01[bb] = MFMA16(A0, B1, zz);
        n10[bb] = MFMA16(A1, B0, zz);
        n11[bb] = MFMA16(A1, B1, zz);
      }
      __builtin_amdgcn_s_barrier();   // all W reads complete before overwrite
      #pragma unroll
      for (int bb = 0; bb < 4; ++bb) {
        const int bx = (4 * w + bb) * 1024 + (m16 >> 2) * 256 + (m16 & 3);
        #pragma unroll
        for (int rr = 0; rr < 4; ++rr) {
          const int pA = (g4 * 4 + rr) * 8, pB = (16 + g4 * 4 + rr) * 8;
          Wl[bx + pA]     = (f16)n00[bb][rr];   // pf=0, nf=0
          Wl[bx + pA + 4] = (f16)n01[bb][rr];   // pf=0, nf=1
          Wl[bx + pB]     = (f16)n10[bb][rr];   // pf=1, nf=0
          Wl[bx + pB + 4] = (f16)n11[bb][rr];   // pf=1, nf=1
        }
      }
      asm volatile("s_waitcnt lgkmcnt(0)" ::: "memory");
      __builtin_amdgcn_s_barrier();
    }
  }

  // ---- epilogue: exchange u = W0[0,:] and fold ----
  if (g == 0) {
    #pragma unroll
    for (int rep = 0; rep < 2; ++rep) {
      const int e = tid + rep * 512;          // e = bb*32 + m
      const int bb = e >> 5, m = e & 31;
      const float v = (float)Wl[bb * 1024 + ((m >> 2) & 3) * 256 + (m >> 4) * 4 + (m & 3)];
      __hip_atomic_store(uex + bt * 1024 + e, v, __ATOMIC_RELAXED, __HIP_MEMORY_SCOPE_AGENT);
    }
    __syncthreads();
    if (tid == 0)
      __hip_atomic_store(flag + bt, 1, __ATOMIC_RELEASE, __HIP_MEMORY_SCOPE_AGENT);
  } else {
    if (tid == 0) {
      while (__hip_atomic_load(flag + bt, __ATOMIC_ACQUIRE, __HIP_MEMORY_SCOPE_AGENT) == 0)
        __builtin_amdgcn_s_sleep(16);
    }
    __syncthreads();
    #pragma unroll
    for (int rep = 0; rep < 2; ++rep) {
      const int e = tid + rep * 512;
      u_lds[e] = __hip_atomic_load(uex + bt * 1024 + e, __ATOMIC_RELAXED, __HIP_MEMORY_SCOPE_AGENT);
    }
    __syncthreads();
    if (tid < 256) {
      const int bb = tid >> 3, o = tid & 7;
      float s = 0.f;
      #pragma unroll
      for (int rho = 0; rho < 32; ++rho)
        s += u_lds[bb * 32 + rho] *
             (float)Wl[bb * 1024 + (o >> 2) * 256 + rho * 8 + (o & 3)];
      out[(size_t)(b0 + bb) * OUT_ + o] = s * 0x1p96f;   // undo (1/8)^32 scaling
    }
  }
}

extern "C" void kernel_launch(void* const* d_in, const int* in_sizes, int n_in,
                              void* d_out, int out_size, void* d_ws, size_t ws_size,
                              hipStream_t stream) {
  (void)in_sizes; (void)n_in; (void)out_size; (void)ws_size;
  const float* action = (const float*)d_in[0];
  const float* obs    = (const float*)d_in[1];
  const float* Wa0 = (const float*)d_in[2];
  const float* ba0 = (const float*)d_in[3];
  const float* Wa1 = (const float*)d_in[4];
  const float* ba1 = (const float*)d_in[5];
  const float* Wo0 = (const float*)d_in[6];
  const float* bo0 = (const float*)d_in[7];
  const float* Wo1 = (const float*)d_in[8];
  const float* bo1 = (const float*)d_in[9];
  const float* Hf  = (const float*)d_in[10];
  const float* Hm  = (const float*)d_in[11];
  const float* Hl  = (const float*)d_in[12];
  char*  ws  = (char*)d_ws;
  float* out = (float*)d_out;

  k_fuse_w<<<1, 256, 0, stream>>>(Wa0, ba0, Wa1, ba1, Wo0, bo0, Wo1, bo1, (float*)ws);
  k_encode<<<(B_ * T_) / 64, 256, 0, stream>>>(action, obs, (const float*)ws,
                                               (f16*)(ws + WS_AENC), (f16*)(ws + WS_OENC));
  k_hprep<<<4096, 256, 0, stream>>>(Hf, Hm, Hl, (f16*)(ws + WS_H));
  hipMemsetAsync(ws + WS_FLAG, 0, 512, stream);   // reset exchange flags every launch
  k_main<<<256, 512, 0, stream>>>((const f16*)(ws + WS_AENC), (const f16*)(ws + WS_OENC),
                                  (const char*)(ws + WS_H), (float*)(ws + WS_U),
                                  (int*)(ws + WS_FLAG), out);
}

// Round 9
// 180.745 us; speedup vs baseline: 1.9268x; 1.2393x over previous
//
#include <hip/hip_runtime.h>

// Problem constants
#define B_    4096
#define T_    32
#define OUT_  8
#define BTILE 32

typedef _Float16 f16;
typedef _Float16 f16x4 __attribute__((ext_vector_type(4)));
typedef _Float16 f16x8 __attribute__((ext_vector_type(8)));
typedef float    f32x4 __attribute__((ext_vector_type(4)));

#define MFMA16(a, b, c) __builtin_amdgcn_mfma_f32_16x16x32_f16((a), (b), (c), 0, 0, 0)

// ---- workspace layout (bytes). Total ~25 MB ----
#define WS_AENC 16384u                    // [B*T][16] f16 = 4 MB
#define WS_OENC (WS_AENC + 4194304u)      // 4 MB
#define WS_H    (WS_OENC + 4194304u)      // f16 relaid H: 16 MB
#define WS_U    (WS_H + 16842752u)        // u exchange: 128 bt x 32 b x 32 m f32 = 512 KB
#define WS_FLAG (WS_U + 524288u)          // 128 ints
// H granule (1 KB) per (t, p, sl, nf): byte ((t*32+p)*16 + sl*2 + nf)*1024 + lane*16
// slot h*4+r = Ht[p][j=2sl+h][kk=g4*4+r][l=nf*16+m16] * (1/8)

// LDS W/M layout (f16 elements), bank-conflict-padded:
//   idx(b, k, n) = b*1064 + ((k>>2)&3)*264 + n*8 + (k>>4)*4 + (k&3)
#define BSTR 1064
#define KGRP 264
#define WSZ  (32 * BSTR)   // 34048 f16 = 68096 B

// ------------------- prep 1: fuse encoder weights -------------------
__global__ void k_fuse_w(const float* __restrict__ Wa0, const float* __restrict__ ba0,
                         const float* __restrict__ Wa1, const float* __restrict__ ba1,
                         const float* __restrict__ Wo0, const float* __restrict__ bo0,
                         const float* __restrict__ Wo1, const float* __restrict__ bo1,
                         float* __restrict__ ws) {
  const int tid = threadIdx.x;  // 256 threads, 1 block
  for (int idx = tid; idx < 1024; idx += 256) {
    const int d = idx >> 4, j = idx & 15;
    float s = 0.f, s2 = 0.f;
    for (int h = 0; h < 128; ++h) {
      s  += Wa0[d * 128 + h] * Wa1[h * 16 + j];
      s2 += Wo0[d * 128 + h] * Wo1[h * 16 + j];
    }
    ws[idx] = s;
    ws[1024 + idx] = s2;
  }
  if (tid < 16) {
    float s = 0.f, s2 = 0.f;
    for (int h = 0; h < 128; ++h) {
      s  += ba0[h] * Wa1[h * 16 + tid];
      s2 += bo0[h] * Wo1[h * 16 + tid];
    }
    ws[2048 + tid] = s + ba1[tid];
    ws[2112 + tid] = s2 + bo1[tid];
  }
}

// ------------------- prep 2: MFMA encoder (f16 in, f32 acc) -------------------
__global__ void k_encode(const float* __restrict__ action, const float* __restrict__ obs,
                         const float* __restrict__ ws,
                         f16* __restrict__ aenc, f16* __restrict__ oenc) {
  const int tid = threadIdx.x;
  const int lane = tid & 63;
  const int v = tid >> 6;
  const int m16 = lane & 15, g4 = lane >> 4;
  const int bt0 = blockIdx.x * 64 + v * 16;

  f16x8 wbA[2], wbB[2];
  #pragma unroll
  for (int ks = 0; ks < 2; ++ks)
    #pragma unroll
    for (int h = 0; h < 2; ++h)
      #pragma unroll
      for (int r = 0; r < 4; ++r) {
        const int d = ks * 32 + h * 16 + g4 * 4 + r;
        wbA[ks][h * 4 + r] = (f16)ws[d * 16 + m16];
        wbB[ks][h * 4 + r] = (f16)ws[1024 + d * 16 + m16];
      }
  const float biasA = ws[2048 + m16], biasB = ws[2112 + m16];
  f32x4 accA = {biasA, biasA, biasA, biasA};
  f32x4 accB = {biasB, biasB, biasB, biasB};

  const float* ar = action + (size_t)(bt0 + m16) * 64;
  const float* br = obs    + (size_t)(bt0 + m16) * 64;
  #pragma unroll
  for (int ks = 0; ks < 2; ++ks) {
    f16x8 aa, oo;
    #pragma unroll
    for (int h = 0; h < 2; ++h) {
      const f32x4 a4 = *(const f32x4*)(ar + ks * 32 + h * 16 + g4 * 4);
      const f32x4 o4 = *(const f32x4*)(br + ks * 32 + h * 16 + g4 * 4);
      #pragma unroll
      for (int r = 0; r < 4; ++r) { aa[h * 4 + r] = (f16)a4[r]; oo[h * 4 + r] = (f16)o4[r]; }
    }
    accA = MFMA16(aa, wbA[ks], accA);
    accB = MFMA16(oo, wbB[ks], accB);
  }
  #pragma unroll
  for (int r = 0; r < 4; ++r) {
    aenc[(size_t)(bt0 + g4 * 4 + r) * 16 + m16] = (f16)accA[r];
    oenc[(size_t)(bt0 + g4 * 4 + r) * 16 + m16] = (f16)accB[r];
  }
}

// ------------------- prep 3: relayout H -> f16 granules, scaled by 1/8 -------------------
__global__ void k_hprep(const float* __restrict__ Hf, const float* __restrict__ Hm,
                        const float* __restrict__ Hl, f16* __restrict__ hdst) {
  const int x = blockIdx.x * 256 + threadIdx.x;     // < 1048576
  const int lane = x & 63;
  const int gid = x >> 6;
  const int nf = gid & 1, s = (gid >> 1) & 7, p = (gid >> 4) & 31, t = gid >> 9;
  const int m16 = lane & 15, g4 = lane >> 4;
  const int l = nf * 16 + m16;
  f16x8 gout;
  #pragma unroll
  for (int h = 0; h < 2; ++h) {
    const int j = 2 * s + h;
    #pragma unroll
    for (int r = 0; r < 4; ++r) {
      const int kk = g4 * 4 + r;
      float vsrc;
      if (t == 0)       vsrc = (p == 0) ? Hf[(j * 16 + kk) * 32 + l] : 0.f;
      else if (t == 31) vsrc = (l < 8) ? Hl[((p * 16 + j) * 16 + kk) * 8 + l] : 0.f;
      else              vsrc = Hm[((((size_t)(t - 1) * 32 + p) * 16 + j) * 16 + kk) * 32 + l];
      gout[h * 4 + r] = (f16)(vsrc * 0.125f);
    }
  }
  *(f16x8*)((char*)hdst + (size_t)x * 16) = gout;
}

// ------------------- main fused kernel: associative 2-way T-split -------------------
// 256 blocks x 512 threads (1 block/CU). Block (bt, g): b-rows [32bt, +32), t in [16g, +16).
// Per tau: [M-form (128 MFMA/wave) + packed M-store] bar [W-read + 16 MFMA] bar [W-store].
__launch_bounds__(512)
__global__ void k_main(const f16* __restrict__ aenc, const f16* __restrict__ oenc,
                       const char* __restrict__ hws, float* __restrict__ uex,
                       int* __restrict__ flag, float* __restrict__ out) {
  __shared__ __align__(16) f16 Wl[WSZ];     // 66.5 KB
  __shared__ __align__(16) f16 Ml[WSZ];     // 66.5 KB
  __shared__ float u_lds[1024];             // 4 KB

  const int tid  = threadIdx.x;
  const int lane = tid & 63;
  const int w    = tid >> 6;       // 0..7 ; wave owns p in [4w, 4w+4)
  const int m16  = lane & 15;
  const int g4   = lane >> 4;
  const int bt   = blockIdx.x >> 1;
  const int g    = blockIdx.x & 1;
  const int b0   = bt * BTILE;
  const int t0   = g * 16;

  // ---- enc regs for t = t0 ----
  const f16* ap0 = aenc + ((size_t)(b0 + m16) * T_ + t0) * 16;
  const f16* ap1 = aenc + ((size_t)(b0 + 16 + m16) * T_ + t0) * 16;
  f16x8 aL0 = *(const f16x8*)ap0, aH0 = *(const f16x8*)(ap0 + 8);
  f16x8 aL1 = *(const f16x8*)ap1, aH1 = *(const f16x8*)(ap1 + 8);
  f16x4 ovA = *(const f16x4*)(oenc + ((size_t)(b0 + m16) * T_ + t0) * 16 + g4 * 4);
  f16x4 ovB = *(const f16x4*)(oenc + ((size_t)(b0 + 16 + m16) * T_ + t0) * 16 + g4 * 4);

  const char* hl = hws + (size_t)lane * 16;
  const f32x4 zz = {0.f, 0.f, 0.f, 0.f};

  f16x8 bufA[8], bufB[8];
  {
    const char* ga = hl + (size_t)((t0 * 32 + 4 * w) * 16) * 1024;
    #pragma unroll
    for (int i = 0; i < 8; ++i) bufA[i] = *(const f16x8*)(ga + i * 1024);
  }

  #pragma clang loop unroll(disable)
  for (int tau = 0; tau < 16; ++tau) {
    const int t = t0 + tau;
    // ---- build E fragments (reused across all p) ----
    f16x8 efr0[8], efr1[8];
    #pragma unroll
    for (int sl = 0; sl < 8; ++sl) {
      const f16 a00 = (sl < 4) ? aL0[2 * sl]     : aH0[2 * sl - 8];
      const f16 a01 = (sl < 4) ? aL0[2 * sl + 1] : aH0[2 * sl - 7];
      const f16 a10 = (sl < 4) ? aL1[2 * sl]     : aH1[2 * sl - 8];
      const f16 a11 = (sl < 4) ? aL1[2 * sl + 1] : aH1[2 * sl - 7];
      #pragma unroll
      for (int r = 0; r < 4; ++r) {
        efr0[sl][r] = a00 * ovA[r]; efr0[sl][4 + r] = a01 * ovA[r];
        efr1[sl][r] = a10 * ovB[r]; efr1[sl][4 + r] = a11 * ovB[r];
      }
    }
    // prefetch next-tau enc (enc regs dead after E build)
    const int tn = (tau < 15) ? t + 1 : t;
    {
      const f16* an0 = aenc + ((size_t)(b0 + m16) * T_ + tn) * 16;
      const f16* an1 = aenc + ((size_t)(b0 + 16 + m16) * T_ + tn) * 16;
      aL0 = *(const f16x8*)an0; aH0 = *(const f16x8*)(an0 + 8);
      aL1 = *(const f16x8*)an1; aH1 = *(const f16x8*)(an1 + 8);
      ovA = *(const f16x4*)(oenc + ((size_t)(b0 + m16) * T_ + tn) * 16 + g4 * 4);
      ovB = *(const f16x4*)(oenc + ((size_t)(b0 + 16 + m16) * T_ + tn) * 16 + g4 * 4);
    }

    // ---- form M rows p = 4w..4w+3; accumulate all 4 pp for packed stores ----
    f32x4 acc[4][2][2];
    #pragma unroll
    for (int pp = 0; pp < 4; ++pp) {
      const int p = 4 * w + pp;
      acc[pp][0][0] = zz; acc[pp][0][1] = zz; acc[pp][1][0] = zz; acc[pp][1][1] = zz;
      {
        const char* gb = hl + ((size_t)((t * 32 + p) * 16) + 8) * 1024;
        #pragma unroll
        for (int i = 0; i < 8; ++i) bufB[i] = *(const f16x8*)(gb + i * 1024);
      }
      __builtin_amdgcn_s_setprio(1);
      #pragma unroll
      for (int sl = 0; sl < 4; ++sl) {
        acc[pp][0][0] = MFMA16(efr0[sl], bufA[sl * 2 + 0], acc[pp][0][0]);
        acc[pp][1][0] = MFMA16(efr1[sl], bufA[sl * 2 + 0], acc[pp][1][0]);
        acc[pp][0][1] = MFMA16(efr0[sl], bufA[sl * 2 + 1], acc[pp][0][1]);
        acc[pp][1][1] = MFMA16(efr1[sl], bufA[sl * 2 + 1], acc[pp][1][1]);
      }
      __builtin_amdgcn_s_setprio(0);
      {
        const int pnext = (pp < 3) ? p + 1 : 4 * w;
        const int tnext = (pp < 3) ? t : tn;
        const char* ga = hl + (size_t)((tnext * 32 + pnext) * 16) * 1024;
        #pragma unroll
        for (int i = 0; i < 8; ++i) bufA[i] = *(const f16x8*)(ga + i * 1024);
      }
      __builtin_amdgcn_s_setprio(1);
      #pragma unroll
      for (int sl = 4; sl < 8; ++sl) {
        acc[pp][0][0] = MFMA16(efr0[sl], bufB[(sl - 4) * 2 + 0], acc[pp][0][0]);
        acc[pp][1][0] = MFMA16(efr1[sl], bufB[(sl - 4) * 2 + 0], acc[pp][1][0]);
        acc[pp][0][1] = MFMA16(efr0[sl], bufB[(sl - 4) * 2 + 1], acc[pp][0][1]);
        acc[pp][1][1] = MFMA16(efr1[sl], bufB[(sl - 4) * 2 + 1], acc[pp][1][1]);
      }
      __builtin_amdgcn_s_setprio(0);
    }

    // ---- packed M-store: k = 4w+pp -> (k&3)=pp contiguous => f16x4 (b64) writes ----
    // dest base: idx(b, k0=4w, n) = b*BSTR + (w&3)*KGRP + n*8 + (w>>2)*4
    #pragma unroll
    for (int mf = 0; mf < 2; ++mf)
      #pragma unroll
      for (int nf = 0; nf < 2; ++nf)
        #pragma unroll
        for (int r = 0; r < 4; ++r) {
          const int b = mf * 16 + g4 * 4 + r;
          const int n = nf * 16 + m16;
          f16x4 v;
          v[0] = (f16)acc[0][mf][nf][r];
          v[1] = (f16)acc[1][mf][nf][r];
          v[2] = (f16)acc[2][mf][nf][r];
          v[3] = (f16)acc[3][mf][nf][r];
          *(f16x4*)&Ml[b * BSTR + (w & 3) * KGRP + n * 8 + (w >> 2) * 4] = v;
        }
    asm volatile("s_waitcnt lgkmcnt(0)" ::: "memory");
    __builtin_amdgcn_s_barrier();

    if (tau == 0) {
      // W := M (transposed copy: k <-> n)
      #pragma unroll
      for (int rep = 0; rep < 64; ++rep) {
        const int e = tid + rep * 512;
        const int b = e >> 10, k = (e >> 5) & 31, rho = e & 31;
        Wl[b * BSTR + ((k >> 2) & 3) * KGRP + rho * 8 + (k >> 4) * 4 + (k & 3)] =
          Ml[b * BSTR + ((rho >> 2) & 3) * KGRP + k * 8 + (rho >> 4) * 4 + (rho & 3)];
      }
      asm volatile("s_waitcnt lgkmcnt(0)" ::: "memory");
      __builtin_amdgcn_s_barrier();
    } else {
      // W <- W*M : wave w handles b in [4w, 4w+4)
      f32x4 n00[4], n01[4], n10[4], n11[4];
      #pragma unroll
      for (int bb = 0; bb < 4; ++bb) {
        const int bx = (4 * w + bb) * BSTR + g4 * KGRP;
        const f16x8 A0 = *(const f16x8*)&Wl[bx + m16 * 8];
        const f16x8 A1 = *(const f16x8*)&Wl[bx + (16 + m16) * 8];
        const f16x8 B0 = *(const f16x8*)&Ml[bx + m16 * 8];
        const f16x8 B1 = *(const f16x8*)&Ml[bx + (16 + m16) * 8];
        n00[bb] = MFMA16(A0, B0, zz);
        n01[bb] = MFMA16(A0, B1, zz);
        n10[bb] = MFMA16(A1, B0, zz);
        n11[bb] = MFMA16(A1, B1, zz);
      }
      __builtin_amdgcn_s_barrier();   // all W reads complete before overwrite
      #pragma unroll
      for (int bb = 0; bb < 4; ++bb) {
        const int bx = (4 * w + bb) * BSTR + (m16 >> 2) * KGRP + (m16 & 3);
        #pragma unroll
        for (int rr = 0; rr < 4; ++rr) {
          const int pA = (g4 * 4 + rr) * 8, pB = (16 + g4 * 4 + rr) * 8;
          Wl[bx + pA]     = (f16)n00[bb][rr];   // k = m16,    n = g4*4+rr
          Wl[bx + pA + 4] = (f16)n01[bb][rr];   // k = 16+m16
          Wl[bx + pB]     = (f16)n10[bb][rr];   // k = m16,    n = 16+g4*4+rr
          Wl[bx + pB + 4] = (f16)n11[bb][rr];   // k = 16+m16
        }
      }
      // W-store drained by the lgkmcnt(0) before the NEXT tau's bar (or epilogue bar)
    }
  }

  asm volatile("s_waitcnt lgkmcnt(0)" ::: "memory");
  __builtin_amdgcn_s_barrier();

  // ---- epilogue: exchange u = W0[0,:] and fold ----
  if (g == 0) {
    #pragma unroll
    for (int rep = 0; rep < 2; ++rep) {
      const int e = tid + rep * 512;          // e = bb*32 + m
      const int bb = e >> 5, m = e & 31;
      const float v = (float)Wl[bb * BSTR + ((m >> 2) & 3) * KGRP + (m >> 4) * 4 + (m & 3)];
      __hip_atomic_store(uex + bt * 1024 + e, v, __ATOMIC_RELAXED, __HIP_MEMORY_SCOPE_AGENT);
    }
    __syncthreads();
    if (tid == 0)
      __hip_atomic_store(flag + bt, 1, __ATOMIC_RELEASE, __HIP_MEMORY_SCOPE_AGENT);
  } else {
    if (tid == 0) {
      while (__hip_atomic_load(flag + bt, __ATOMIC_ACQUIRE, __HIP_MEMORY_SCOPE_AGENT) == 0)
        __builtin_amdgcn_s_sleep(16);
    }
    __syncthreads();
    #pragma unroll
    for (int rep = 0; rep < 2; ++rep) {
      const int e = tid + rep * 512;
      u_lds[e] = __hip_atomic_load(uex + bt * 1024 + e, __ATOMIC_RELAXED, __HIP_MEMORY_SCOPE_AGENT);
    }
    __syncthreads();
    if (tid < 256) {
      const int bb = tid >> 3, o = tid & 7;
      float s = 0.f;
      #pragma unroll
      for (int rho = 0; rho < 32; ++rho)
        s += u_lds[bb * 32 + rho] *
             (float)Wl[bb * BSTR + (o >> 2) * KGRP + rho * 8 + (o & 3)];
      out[(size_t)(b0 + bb) * OUT_ + o] = s * 0x1p96f;   // undo (1/8)^32 scaling
    }
  }
}

extern "C" void kernel_launch(void* const* d_in, const int* in_sizes, int n_in,
                              void* d_out, int out_size, void* d_ws, size_t ws_size,
                              hipStream_t stream) {
  (void)in_sizes; (void)n_in; (void)out_size; (void)ws_size;
  const float* action = (const float*)d_in[0];
  const float* obs    = (const float*)d_in[1];
  const float* Wa0 = (const float*)d_in[2];
  const float* ba0 = (const float*)d_in[3];
  const float* Wa1 = (const float*)d_in[4];
  const float* ba1 = (const float*)d_in[5];
  const float* Wo0 = (const float*)d_in[6];
  const float* bo0 = (const float*)d_in[7];
  const float* Wo1 = (const float*)d_in[8];
  const float* bo1 = (const float*)d_in[9];
  const float* Hf  = (const float*)d_in[10];
  const float* Hm  = (const float*)d_in[11];
  const float* Hl  = (const float*)d_in[12];
  char*  ws  = (char*)d_ws;
  float* out = (float*)d_out;

  k_fuse_w<<<1, 256, 0, stream>>>(Wa0, ba0, Wa1, ba1, Wo0, bo0, Wo1, bo1, (float*)ws);
  k_encode<<<(B_ * T_) / 64, 256, 0, stream>>>(action, obs, (const float*)ws,
                                               (f16*)(ws + WS_AENC), (f16*)(ws + WS_OENC));
  k_hprep<<<4096, 256, 0, stream>>>(Hf, Hm, Hl, (f16*)(ws + WS_H));
  hipMemsetAsync(ws + WS_FLAG, 0, 512, stream);   // reset exchange flags every launch
  k_main<<<256, 512, 0, stream>>>((const f16*)(ws + WS_AENC), (const f16*)(ws + WS_OENC),
                                  (const char*)(ws + WS_H), (float*)(ws + WS_U),
                                  (int*)(ws + WS_FLAG), out);
}

// Round 10
// 175.456 us; speedup vs baseline: 1.9849x; 1.0301x over previous
//
#include <hip/hip_runtime.h>

// Problem constants
#define B_    4096
#define T_    32
#define OUT_  8
#define BTILE 32

typedef _Float16 f16;
typedef _Float16 f16x2 __attribute__((ext_vector_type(2)));
typedef _Float16 f16x4 __attribute__((ext_vector_type(4)));
typedef _Float16 f16x8 __attribute__((ext_vector_type(8)));
typedef float    f32x4 __attribute__((ext_vector_type(4)));

#define MFMA16(a, b, c) __builtin_amdgcn_mfma_f32_16x16x32_f16((a), (b), (c), 0, 0, 0)

// ---- workspace layout (bytes). Total ~25 MB ----
#define WS_AENC 16384u                    // [B*T][16] f16 = 4 MB
#define WS_OENC (WS_AENC + 4194304u)      // 4 MB
#define WS_H    (WS_OENC + 4194304u)      // f16 relaid H: 16 MB
#define WS_U    (WS_H + 16842752u)        // u exchange: 128 bt x 32 b x 32 m f32 = 512 KB
#define WS_FLAG (WS_U + 524288u)          // 128 ints
// H granule (1 KB) per (t, p, sl, nf): byte ((t*32+p)*16 + sl*2 + nf)*1024 + lane*16
// slot h*4+r = Ht[p][j=2sl+h][kk=g4*4+r][l=nf*16+m16] * (1/8)

// LDS W/M layout (f16 elements), bank-conflict-padded:
//   idx(b, k, n) = b*1064 + ((k>>2)&3)*264 + n*8 + (k>>4)*4 + (k&3)
#define BSTR 1064
#define KGRP 264
#define WSZ  (32 * BSTR)   // 34048 f16 = 68096 B

// ------------------- prep 1: fuse encoder weights -------------------
__global__ void k_fuse_w(const float* __restrict__ Wa0, const float* __restrict__ ba0,
                         const float* __restrict__ Wa1, const float* __restrict__ ba1,
                         const float* __restrict__ Wo0, const float* __restrict__ bo0,
                         const float* __restrict__ Wo1, const float* __restrict__ bo1,
                         float* __restrict__ ws) {
  const int tid = threadIdx.x;  // 256 threads, 1 block
  for (int idx = tid; idx < 1024; idx += 256) {
    const int d = idx >> 4, j = idx & 15;
    float s = 0.f, s2 = 0.f;
    for (int h = 0; h < 128; ++h) {
      s  += Wa0[d * 128 + h] * Wa1[h * 16 + j];
      s2 += Wo0[d * 128 + h] * Wo1[h * 16 + j];
    }
    ws[idx] = s;
    ws[1024 + idx] = s2;
  }
  if (tid < 16) {
    float s = 0.f, s2 = 0.f;
    for (int h = 0; h < 128; ++h) {
      s  += ba0[h] * Wa1[h * 16 + tid];
      s2 += bo0[h] * Wo1[h * 16 + tid];
    }
    ws[2048 + tid] = s + ba1[tid];
    ws[2112 + tid] = s2 + bo1[tid];
  }
}

// ------------------- prep 2: MFMA encoder (f16 in, f32 acc) -------------------
__global__ void k_encode(const float* __restrict__ action, const float* __restrict__ obs,
                         const float* __restrict__ ws,
                         f16* __restrict__ aenc, f16* __restrict__ oenc) {
  const int tid = threadIdx.x;
  const int lane = tid & 63;
  const int v = tid >> 6;
  const int m16 = lane & 15, g4 = lane >> 4;
  const int bt0 = blockIdx.x * 64 + v * 16;

  f16x8 wbA[2], wbB[2];
  #pragma unroll
  for (int ks = 0; ks < 2; ++ks)
    #pragma unroll
    for (int h = 0; h < 2; ++h)
      #pragma unroll
      for (int r = 0; r < 4; ++r) {
        const int d = ks * 32 + h * 16 + g4 * 4 + r;
        wbA[ks][h * 4 + r] = (f16)ws[d * 16 + m16];
        wbB[ks][h * 4 + r] = (f16)ws[1024 + d * 16 + m16];
      }
  const float biasA = ws[2048 + m16], biasB = ws[2112 + m16];
  f32x4 accA = {biasA, biasA, biasA, biasA};
  f32x4 accB = {biasB, biasB, biasB, biasB};

  const float* ar = action + (size_t)(bt0 + m16) * 64;
  const float* br = obs    + (size_t)(bt0 + m16) * 64;
  #pragma unroll
  for (int ks = 0; ks < 2; ++ks) {
    f16x8 aa, oo;
    #pragma unroll
    for (int h = 0; h < 2; ++h) {
      const f32x4 a4 = *(const f32x4*)(ar + ks * 32 + h * 16 + g4 * 4);
      const f32x4 o4 = *(const f32x4*)(br + ks * 32 + h * 16 + g4 * 4);
      #pragma unroll
      for (int r = 0; r < 4; ++r) { aa[h * 4 + r] = (f16)a4[r]; oo[h * 4 + r] = (f16)o4[r]; }
    }
    accA = MFMA16(aa, wbA[ks], accA);
    accB = MFMA16(oo, wbB[ks], accB);
  }
  #pragma unroll
  for (int r = 0; r < 4; ++r) {
    aenc[(size_t)(bt0 + g4 * 4 + r) * 16 + m16] = (f16)accA[r];
    oenc[(size_t)(bt0 + g4 * 4 + r) * 16 + m16] = (f16)accB[r];
  }
}

// ------------------- prep 3: relayout H -> f16 granules, scaled by 1/8 -------------------
__global__ void k_hprep(const float* __restrict__ Hf, const float* __restrict__ Hm,
                        const float* __restrict__ Hl, f16* __restrict__ hdst) {
  const int x = blockIdx.x * 256 + threadIdx.x;     // < 1048576
  const int lane = x & 63;
  const int gid = x >> 6;
  const int nf = gid & 1, s = (gid >> 1) & 7, p = (gid >> 4) & 31, t = gid >> 9;
  const int m16 = lane & 15, g4 = lane >> 4;
  const int l = nf * 16 + m16;
  f16x8 gout;
  #pragma unroll
  for (int h = 0; h < 2; ++h) {
    const int j = 2 * s + h;
    #pragma unroll
    for (int r = 0; r < 4; ++r) {
      const int kk = g4 * 4 + r;
      float vsrc;
      if (t == 0)       vsrc = (p == 0) ? Hf[(j * 16 + kk) * 32 + l] : 0.f;
      else if (t == 31) vsrc = (l < 8) ? Hl[((p * 16 + j) * 16 + kk) * 8 + l] : 0.f;
      else              vsrc = Hm[((((size_t)(t - 1) * 32 + p) * 16 + j) * 16 + kk) * 32 + l];
      gout[h * 4 + r] = (f16)(vsrc * 0.125f);
    }
  }
  *(f16x8*)((char*)hdst + (size_t)x * 16) = gout;
}

// ------------------- main fused kernel: associative 2-way T-split -------------------
// 256 blocks x 512 threads (1 block/CU). Block (bt, g): b-rows [32bt, +32), t in [16g, +16).
// M-form streams H via a ring of 4 register units (8 granules each), load-use distance
// = 2 units (~32 MFMA). E-fragments built on the fly (VALU overlaps MFMA pipe).
__launch_bounds__(512)
__attribute__((amdgpu_waves_per_eu(2, 2)))
__global__ void k_main(const f16* __restrict__ aenc, const f16* __restrict__ oenc,
                       const char* __restrict__ hws, float* __restrict__ uex,
                       int* __restrict__ flag, float* __restrict__ out) {
  __shared__ __align__(16) f16 Wl[WSZ];     // 66.5 KB
  __shared__ __align__(16) f16 Ml[WSZ];     // 66.5 KB
  __shared__ float u_lds[1024];             // 4 KB

  const int tid  = threadIdx.x;
  const int lane = tid & 63;
  const int w    = tid >> 6;       // 0..7 ; wave owns p in [4w, 4w+4)
  const int m16  = lane & 15;
  const int g4   = lane >> 4;
  const int bt   = blockIdx.x >> 1;
  const int g    = blockIdx.x & 1;
  const int b0   = bt * BTILE;
  const int t0   = g * 16;

  // ---- enc regs for t = t0 ----
  const f16* ap0 = aenc + ((size_t)(b0 + m16) * T_ + t0) * 16;
  const f16* ap1 = aenc + ((size_t)(b0 + 16 + m16) * T_ + t0) * 16;
  f16x8 aL0 = *(const f16x8*)ap0, aH0 = *(const f16x8*)(ap0 + 8);
  f16x8 aL1 = *(const f16x8*)ap1, aH1 = *(const f16x8*)(ap1 + 8);
  f16x4 ovA = *(const f16x4*)(oenc + ((size_t)(b0 + m16) * T_ + t0) * 16 + g4 * 4);
  f16x4 ovB = *(const f16x4*)(oenc + ((size_t)(b0 + 16 + m16) * T_ + t0) * 16 + g4 * 4);

  const char* hl = hws + (size_t)lane * 16;
  const f32x4 zz = {0.f, 0.f, 0.f, 0.f};

  // ring of 4 H units; unit QQ of timestep TT: p = 4w + (QQ>>1), granules (QQ&1)*8 .. +8
  f16x8 u0[8], u1[8], u2[8], u3[8];

#define ULOAD(U, TT, QQ) do {                                                  \
    const char* ga_ = hl + (size_t)((((TT) * 32 + 4 * w + ((QQ) >> 1)) * 16    \
                                    + ((QQ) & 1) * 8)) * 1024;                 \
    _Pragma("unroll")                                                          \
    for (int i_ = 0; i_ < 8; ++i_) U[i_] = *(const f16x8*)(ga_ + i_ * 1024);   \
  } while (0)

  // compute one unit: half H (sl = 4H..4H+3) of some p, accumulating into ACC[mf][nf]
#define UCOMP(U, ACC, H) do {                                                  \
    __builtin_amdgcn_s_setprio(1);                                             \
    _Pragma("unroll")                                                          \
    for (int s2_ = 0; s2_ < 4; ++s2_) {                                        \
      const int sl_ = 4 * (H) + s2_;                                           \
      const f16 a00 = (sl_ < 4) ? aL0[2 * sl_]     : aH0[2 * sl_ - 8];         \
      const f16 a01 = (sl_ < 4) ? aL0[2 * sl_ + 1] : aH0[2 * sl_ - 7];         \
      const f16 a10 = (sl_ < 4) ? aL1[2 * sl_]     : aH1[2 * sl_ - 8];         \
      const f16 a11 = (sl_ < 4) ? aL1[2 * sl_ + 1] : aH1[2 * sl_ - 7];         \
      f16x8 af0, af1;                                                          \
      _Pragma("unroll")                                                        \
      for (int r_ = 0; r_ < 4; ++r_) {                                         \
        af0[r_] = a00 * ovA[r_]; af0[4 + r_] = a01 * ovA[r_];                  \
        af1[r_] = a10 * ovB[r_]; af1[4 + r_] = a11 * ovB[r_];                  \
      }                                                                        \
      ACC[0][0] = MFMA16(af0, U[2 * s2_],     ACC[0][0]);                      \
      ACC[0][1] = MFMA16(af0, U[2 * s2_ + 1], ACC[0][1]);                      \
      ACC[1][0] = MFMA16(af1, U[2 * s2_],     ACC[1][0]);                      \
      ACC[1][1] = MFMA16(af1, U[2 * s2_ + 1], ACC[1][1]);                      \
    }                                                                          \
    __builtin_amdgcn_s_setprio(0);                                             \
  } while (0)

  // store a pp-pair (P0 = even, P1 = odd member) at byte offset OFF within the k-quad
#define MSTORE(OFF) do {                                                       \
    _Pragma("unroll")                                                          \
    for (int mf_ = 0; mf_ < 2; ++mf_)                                          \
      _Pragma("unroll")                                                        \
      for (int nf_ = 0; nf_ < 2; ++nf_)                                        \
        _Pragma("unroll")                                                      \
        for (int r_ = 0; r_ < 4; ++r_) {                                       \
          const int b_ = mf_ * 16 + g4 * 4 + r_;                               \
          const int n_ = nf_ * 16 + m16;                                       \
          f16x2 v_;                                                            \
          v_[0] = (f16)accP0[mf_][nf_][r_];                                    \
          v_[1] = (f16)accP1[mf_][nf_][r_];                                    \
          *(f16x2*)((char*)Ml + 2 * (b_ * BSTR + (w & 3) * KGRP + n_ * 8       \
                                     + (w >> 2) * 4) + (OFF)) = v_;            \
        }                                                                      \
  } while (0)

  // prologue: units 0,1 of t0
  ULOAD(u0, t0, 0);
  ULOAD(u1, t0, 1);

  #pragma clang loop unroll(disable)
  for (int tau = 0; tau < 16; ++tau) {
    const int t = t0 + tau;
    const int tn = (tau < 15) ? t + 1 : t;

    f32x4 accP0[2][2], accP1[2][2];
    #pragma unroll
    for (int mf = 0; mf < 2; ++mf)
      #pragma unroll
      for (int nf = 0; nf < 2; ++nf) { accP0[mf][nf] = zz; accP1[mf][nf] = zz; }

    // ---- M-form: 8 units, ring-4, prefetch distance 2 ----
    ULOAD(u2, t, 2);  UCOMP(u0, accP0, 0);   // q=0: pp0 h0
    ULOAD(u3, t, 3);  UCOMP(u1, accP0, 1);   // q=1: pp0 h1
    ULOAD(u0, t, 4);  UCOMP(u2, accP1, 0);   // q=2: pp1 h0
    ULOAD(u1, t, 5);  UCOMP(u3, accP1, 1);   // q=3: pp1 h1
    MSTORE(0);                               // store pp0, pp1
    #pragma unroll
    for (int mf = 0; mf < 2; ++mf)
      #pragma unroll
      for (int nf = 0; nf < 2; ++nf) { accP0[mf][nf] = zz; accP1[mf][nf] = zz; }
    ULOAD(u2, t, 6);   UCOMP(u0, accP0, 0);  // q=4: pp2 h0
    ULOAD(u3, t, 7);   UCOMP(u1, accP0, 1);  // q=5: pp2 h1
    ULOAD(u0, tn, 0);  UCOMP(u2, accP1, 0);  // q=6: pp3 h0 (+ next-tau prefetch)
    ULOAD(u1, tn, 1);  UCOMP(u3, accP1, 1);  // q=7: pp3 h1
    MSTORE(4);                               // store pp2, pp3

    // stage next-tau enc inputs (enc regs dead after q=7)
    {
      const f16* an0 = aenc + ((size_t)(b0 + m16) * T_ + tn) * 16;
      const f16* an1 = aenc + ((size_t)(b0 + 16 + m16) * T_ + tn) * 16;
      aL0 = *(const f16x8*)an0; aH0 = *(const f16x8*)(an0 + 8);
      aL1 = *(const f16x8*)an1; aH1 = *(const f16x8*)(an1 + 8);
      ovA = *(const f16x4*)(oenc + ((size_t)(b0 + m16) * T_ + tn) * 16 + g4 * 4);
      ovB = *(const f16x4*)(oenc + ((size_t)(b0 + 16 + m16) * T_ + tn) * 16 + g4 * 4);
    }

    asm volatile("s_waitcnt lgkmcnt(0)" ::: "memory");
    __builtin_amdgcn_s_barrier();

    if (tau == 0) {
      // W := M (transposed copy: k <-> n)
      #pragma unroll
      for (int rep = 0; rep < 64; ++rep) {
        const int e = tid + rep * 512;
        const int b = e >> 10, k = (e >> 5) & 31, rho = e & 31;
        Wl[b * BSTR + ((k >> 2) & 3) * KGRP + rho * 8 + (k >> 4) * 4 + (k & 3)] =
          Ml[b * BSTR + ((rho >> 2) & 3) * KGRP + k * 8 + (rho >> 4) * 4 + (rho & 3)];
      }
      asm volatile("s_waitcnt lgkmcnt(0)" ::: "memory");
      __builtin_amdgcn_s_barrier();
    } else {
      // W <- W*M : wave w handles b in [4w, 4w+4)
      f32x4 n00[4], n01[4], n10[4], n11[4];
      #pragma unroll
      for (int bb = 0; bb < 4; ++bb) {
        const int bx = (4 * w + bb) * BSTR + g4 * KGRP;
        const f16x8 A0 = *(const f16x8*)&Wl[bx + m16 * 8];
        const f16x8 A1 = *(const f16x8*)&Wl[bx + (16 + m16) * 8];
        const f16x8 B0 = *(const f16x8*)&Ml[bx + m16 * 8];
        const f16x8 B1 = *(const f16x8*)&Ml[bx + (16 + m16) * 8];
        n00[bb] = MFMA16(A0, B0, zz);
        n01[bb] = MFMA16(A0, B1, zz);
        n10[bb] = MFMA16(A1, B0, zz);
        n11[bb] = MFMA16(A1, B1, zz);
      }
      __builtin_amdgcn_s_barrier();   // all W reads complete before overwrite
      #pragma unroll
      for (int bb = 0; bb < 4; ++bb) {
        const int bx = (4 * w + bb) * BSTR + (m16 >> 2) * KGRP + (m16 & 3);
        #pragma unroll
        for (int rr = 0; rr < 4; ++rr) {
          const int pA = (g4 * 4 + rr) * 8, pB = (16 + g4 * 4 + rr) * 8;
          Wl[bx + pA]     = (f16)n00[bb][rr];   // k = m16,    n = g4*4+rr
          Wl[bx + pA + 4] = (f16)n01[bb][rr];   // k = 16+m16
          Wl[bx + pB]     = (f16)n10[bb][rr];   // k = m16,    n = 16+g4*4+rr
          Wl[bx + pB + 4] = (f16)n11[bb][rr];   // k = 16+m16
        }
      }
      // W-store drained by the lgkmcnt(0) before the NEXT tau's barrier (or epilogue)
    }
  }

  asm volatile("s_waitcnt lgkmcnt(0)" ::: "memory");
  __builtin_amdgcn_s_barrier();

  // ---- epilogue: exchange u = W0[0,:] and fold ----
  if (g == 0) {
    #pragma unroll
    for (int rep = 0; rep < 2; ++rep) {
      const int e = tid + rep * 512;          // e = bb*32 + m
      const int bb = e >> 5, m = e & 31;
      const float v = (float)Wl[bb * BSTR + ((m >> 2) & 3) * KGRP + (m >> 4) * 4 + (m & 3)];
      __hip_atomic_store(uex + bt * 1024 + e, v, __ATOMIC_RELAXED, __HIP_MEMORY_SCOPE_AGENT);
    }
    __syncthreads();
    if (tid == 0)
      __hip_atomic_store(flag + bt, 1, __ATOMIC_RELEASE, __HIP_MEMORY_SCOPE_AGENT);
  } else {
    if (tid == 0) {
      while (__hip_atomic_load(flag + bt, __ATOMIC_ACQUIRE, __HIP_MEMORY_SCOPE_AGENT) == 0)
        __builtin_amdgcn_s_sleep(16);
    }
    __syncthreads();
    #pragma unroll
    for (int rep = 0; rep < 2; ++rep) {
      const int e = tid + rep * 512;
      u_lds[e] = __hip_atomic_load(uex + bt * 1024 + e, __ATOMIC_RELAXED, __HIP_MEMORY_SCOPE_AGENT);
    }
    __syncthreads();
    if (tid < 256) {
      const int bb = tid >> 3, o = tid & 7;
      float s = 0.f;
      #pragma unroll
      for (int rho = 0; rho < 32; ++rho)
        s += u_lds[bb * 32 + rho] *
             (float)Wl[bb * BSTR + (o >> 2) * KGRP + rho * 8 + (o & 3)];
      out[(size_t)(b0 + bb) * OUT_ + o] = s * 0x1p96f;   // undo (1/8)^32 scaling
    }
  }
#undef ULOAD
#undef UCOMP
#undef MSTORE
}

extern "C" void kernel_launch(void* const* d_in, const int* in_sizes, int n_in,
                              void* d_out, int out_size, void* d_ws, size_t ws_size,
                              hipStream_t stream) {
  (void)in_sizes; (void)n_in; (void)out_size; (void)ws_size;
  const float* action = (const float*)d_in[0];
  const float* obs    = (const float*)d_in[1];
  const float* Wa0 = (const float*)d_in[2];
  const float* ba0 = (const float*)d_in[3];
  const float* Wa1 = (const float*)d_in[4];
  const float* ba1 = (const float*)d_in[5];
  const float* Wo0 = (const float*)d_in[6];
  const float* bo0 = (const float*)d_in[7];
  const float* Wo1 = (const float*)d_in[8];
  const float* bo1 = (const float*)d_in[9];
  const float* Hf  = (const float*)d_in[10];
  const float* Hm  = (const float*)d_in[11];
  const float* Hl  = (const float*)d_in[12];
  char*  ws  = (char*)d_ws;
  float* out = (float*)d_out;

  k_fuse_w<<<1, 256, 0, stream>>>(Wa0, ba0, Wa1, ba1, Wo0, bo0, Wo1, bo1, (float*)ws);
  k_encode<<<(B_ * T_) / 64, 256, 0, stream>>>(action, obs, (const float*)ws,
                                               (f16*)(ws + WS_AENC), (f16*)(ws + WS_OENC));
  k_hprep<<<4096, 256, 0, stream>>>(Hf, Hm, Hl, (f16*)(ws + WS_H));
  hipMemsetAsync(ws + WS_FLAG, 0, 512, stream);   // reset exchange flags every launch
  k_main<<<256, 512, 0, stream>>>((const f16*)(ws + WS_AENC), (const f16*)(ws + WS_OENC),
                                  (const char*)(ws + WS_H), (float*)(ws + WS_U),
                                  (int*)(ws + WS_FLAG), out);
}